// Round 15
// baseline (829.728 us; speedup 1.0000x reference)
//
#include <hip/hip_runtime.h>

// GNN forward: 3 x (edge-MLP -> GAT(softmax over col) -> BN+ReLU) -> mean-pool -> MLP.
// Round-15: (a) combined row table xrH=[xa|xw] (256B rows): edge_mlp's existing xa
// row gather widened to also fetch xw, streamed out as xwe[e]=xw[srow[e]] in sorted
// order -> col_agg's random gather becomes a contiguous stream (drops srow read too).
// (b) 3-phase parallel scan replaces the 49-iteration single-block scan.
// Numerics identical to round 14 (same bf16 values, new routing).

#define NN 50000
#define NE 800000
#define NEG_SLOPE 0.2f

typedef __attribute__((ext_vector_type(8))) __bf16 bf16x8;
typedef __attribute__((ext_vector_type(4))) float f32x4;

__device__ __forceinline__ float4 ld4(const float* __restrict__ p){ return *(const float4* __restrict__)p; }
__device__ __forceinline__ float4 f4zero(){ return make_float4(0.f,0.f,0.f,0.f); }
__device__ __forceinline__ bf16x8 cvt8(float4 a, float4 b){
  bf16x8 r;
  r[0]=(__bf16)a.x; r[1]=(__bf16)a.y; r[2]=(__bf16)a.z; r[3]=(__bf16)a.w;
  r[4]=(__bf16)b.x; r[5]=(__bf16)b.y; r[6]=(__bf16)b.z; r[7]=(__bf16)b.w;
  return r;
}
__device__ __forceinline__ bf16x8 addpack8(bf16x8 a, bf16x8 b){
  bf16x8 r;
#pragma unroll
  for (int e = 0; e < 8; ++e) r[e] = (__bf16)((float)a[e] + (float)b[e]);
  return r;
}
__device__ __forceinline__ float4 bnrelu4(float4 v, const float* sc, const float* sh, int d){
  return make_float4(
    fmaxf(fmaf(v.x, sc[d+0], sh[d+0]), 0.f),
    fmaxf(fmaf(v.y, sc[d+1], sh[d+1]), 0.f),
    fmaxf(fmaf(v.z, sc[d+2], sh[d+2]), 0.f),
    fmaxf(fmaf(v.w, sc[d+3], sh[d+3]), 0.f));
}

// ---------------- merged setup: hist + graph bounds + weight fragments
__global__ __launch_bounds__(256) void setup_kernel(
    const int* __restrict__ ei_col, int* __restrict__ cnt,
    const int* __restrict__ batch, int* __restrict__ goff,
    const float* __restrict__ em_w1, const float* __restrict__ em_w2,
    const float* __restrict__ gat_w,
    const float* __restrict__ edge_w, const float* __restrict__ att_edge,
    __bf16* __restrict__ w1f, __bf16* __restrict__ w2f, __bf16* __restrict__ wnf,
    float* __restrict__ vbuf)
{
  const int b = blockIdx.x, t = threadIdx.x;
  if (b < NE/256){
    atomicAdd(&cnt[ei_col[b*256 + t]], 1);
    int n = b*256 + t;
    if (n < NN){
      int bn = batch[n];
      int bp = (n == 0) ? -1 : batch[n-1];
      for (int g = bp + 1; g <= bn; ++g) goff[g] = n;
      if (n == NN - 1){ for (int g = bn + 1; g <= 32; ++g) goff[g] = NN; }
    }
  } else {
    const int l = b - NE/256;
    const float* W1c = em_w1 + l*12288 + 8192;   // rows 128..191 of em_w1[l]
    const float* W2  = em_w2 + l*4096;
    for (int p = t; p < 512; p += 256){
      int li = p & 63, ks = (p >> 6) & 1, nt = p >> 7;
      int kbase = ks*32 + (li >> 4)*8;
      int j = nt*16 + (li & 15);
      bf16x8 v1, v2;
#pragma unroll
      for (int e = 0; e < 8; ++e){
        v1[e] = (__bf16)W1c[(size_t)(kbase+e)*64 + j];
        v2[e] = (__bf16)W2[(size_t)(kbase+e)*64 + j];
      }
      *(bf16x8*)(w1f + (size_t)l*4096 + p*8) = v1;
      *(bf16x8*)(w2f + (size_t)l*4096 + p*8) = v2;
    }
    // node GEMM weights: p=0 W1a (rows 0..63), p=1 W1b (rows 64..127), p=2 gat_w
    for (int pp = t; pp < 1536; pp += 256){
      int p = pp >> 9, piece = pp & 511;
      int li = piece & 63, ks = (piece >> 6) & 1, nt = piece >> 7;
      int kbase = ks*32 + (li >> 4)*8;
      int j = nt*16 + (li & 15);
      const float* W = (p == 0) ? (em_w1 + l*12288)
                     : (p == 1) ? (em_w1 + l*12288 + 4096)
                                : (gat_w + l*4096);
      bf16x8 v;
#pragma unroll
      for (int e = 0; e < 8; ++e) v[e] = (__bf16)W[(size_t)(kbase+e)*64 + j];
      *(bf16x8*)(wnf + (size_t)l*12288 + (size_t)p*4096 + piece*8) = v;
    }
    if (t < 64){
      float a = 0.f;
      const float* ew = edge_w + l*4096 + t*64;
      const float* ae = att_edge + l*64;
#pragma unroll 8
      for (int j = 0; j < 64; ++j) a = fmaf(ew[j], ae[j], a);
      vbuf[l*64 + t] = a;
    }
  }
}

// ---------------- 3-phase parallel exclusive scan over NN bins
__global__ __launch_bounds__(256) void scanA(const int* __restrict__ cnt,
                                             int* __restrict__ soff,
                                             int* __restrict__ btot){
  __shared__ int wsum[4];
  const int b = blockIdx.x, t = threadIdx.x;
  const int lane = t & 63, w = t >> 6;
  int idx = b*256 + t;
  int v = (idx < NN) ? cnt[idx] : 0;
  int x = v;
#pragma unroll
  for (int o = 1; o < 64; o <<= 1){
    int u = __shfl_up(x, o);
    if (lane >= o) x += u;
  }
  if (lane == 63) wsum[w] = x;
  __syncthreads();
  int wo = 0;
#pragma unroll
  for (int k = 0; k < 4; ++k) if (k < w) wo += wsum[k];
  int incl = x + wo;
  if (idx < NN) soff[idx] = incl - v;
  if (t == 255) btot[b] = incl;
}
__global__ __launch_bounds__(256) void scanB(const int* __restrict__ btot,
                                             int* __restrict__ btotex,
                                             int* __restrict__ soff){
  __shared__ int wsum[4];
  const int t = threadIdx.x, lane = t & 63, w = t >> 6;
  int v = (t < 196) ? btot[t] : 0;
  int x = v;
#pragma unroll
  for (int o = 1; o < 64; o <<= 1){
    int u = __shfl_up(x, o);
    if (lane >= o) x += u;
  }
  if (lane == 63) wsum[w] = x;
  __syncthreads();
  int wo = 0;
#pragma unroll
  for (int k = 0; k < 4; ++k) if (k < w) wo += wsum[k];
  int incl = x + wo;
  if (t < 196) btotex[t] = incl - v;
  if (t == 195) soff[NN] = incl;
}
__global__ __launch_bounds__(256) void scanC(int* __restrict__ soff,
                                             const int* __restrict__ btotex){
  int idx = blockIdx.x*256 + threadIdx.x;
  if (idx < NN) soff[idx] += btotex[blockIdx.x];
}

// ---------------- sort: scatter into sorted position
__global__ __launch_bounds__(256) void scatter_kernel(
    const int* __restrict__ ei, const int* __restrict__ off, int* __restrict__ cur,
    int* __restrict__ srow, int* __restrict__ scol, int* __restrict__ perm){
  int e = blockIdx.x * 256 + threadIdx.x;
  int r = ei[e], c = ei[NE + e];
  int pos = off[c] + atomicAdd(&cur[c], 1);
  srow[pos] = r; scol[pos] = c; perm[pos] = e;
}

// ---------------- node prep: single pass, MFMA. Writes xrH=[xa|xw] (128/node) + xbH.
__global__ __launch_bounds__(256) void node_prep(
    const float* __restrict__ x0_in, const float* __restrict__ h_in,
    const float* __restrict__ bnpart,
    const float* __restrict__ gamma, const float* __restrict__ beta,
    const __bf16* __restrict__ wnf_l,   // 3*4096 bf16 (W1a | W1b | gat_w frags)
    const float* __restrict__ b1v,
    const float* __restrict__ asrc_g, const float* __restrict__ adst_g,
    __bf16* __restrict__ xrH, __bf16* __restrict__ xbH,
    float* __restrict__ ssrc, float* __restrict__ sdst, int l)
{
  __shared__ __align__(16) __bf16 xf[64*72];
  __shared__ float sc[64], sh[64];
  __shared__ float b1s[64], asrc[64], adst[64];
  const int t = threadIdx.x;
  const int n0 = blockIdx.x * 64;
  const int w = t >> 6, lane = t & 63, m = lane & 15, kg = lane >> 4;

  if (l > 0){
    if (t < 64){
      float s = 0.f, s2 = 0.f;
#pragma unroll 8
      for (int k = 0; k < 64; ++k){
        s  += bnpart[k*128 + t];
        s2 += bnpart[k*128 + 64 + t];
      }
      float mu  = s * (1.0f / NN);
      float var = s2 * (1.0f / NN) - mu * mu;
      float iv  = rsqrtf(var + 1e-5f) * gamma[(l-1)*64 + t];
      sc[t] = iv;
      sh[t] = beta[(l-1)*64 + t] - mu * iv;
    }
    __syncthreads();
  }
  if (t < 64) b1s[t] = b1v[t];
  else if (t < 128) asrc[t-64] = asrc_g[t-64];
  else if (t < 192) adst[t-128] = adst_g[t-128];

  { const int e_loc = t >> 2, q = t & 3;
    const int n = n0 + e_loc;
    float4 v0, v1, v2, v3;
    if (n < NN){
      const float* src = ((l == 0) ? x0_in : h_in) + (size_t)n*64 + q*16;
      v0 = ld4(src); v1 = ld4(src+4); v2 = ld4(src+8); v3 = ld4(src+12);
      if (l > 0){
        v0 = bnrelu4(v0, sc, sh, q*16);
        v1 = bnrelu4(v1, sc, sh, q*16+4);
        v2 = bnrelu4(v2, sc, sh, q*16+8);
        v3 = bnrelu4(v3, sc, sh, q*16+12);
      }
    } else { v0 = v1 = v2 = v3 = f4zero(); }
    *(bf16x8*)&xf[e_loc*72 + q*16]     = cvt8(v0, v1);
    *(bf16x8*)&xf[e_loc*72 + q*16 + 8] = cvt8(v2, v3);
  }
  __syncthreads();

  const bf16x8 a0 = *(const bf16x8*)&xf[(16*w + m)*72 + kg*8];
  const bf16x8 a1 = *(const bf16x8*)&xf[(16*w + m)*72 + kg*8 + 32];
  const f32x4 z4 = {0.f, 0.f, 0.f, 0.f};

#pragma unroll
  for (int p = 0; p < 3; ++p){
    const bf16x8* Bp = (const bf16x8*)(wnf_l + (size_t)p*4096);
    f32x4 acc[4];
#pragma unroll
    for (int nt = 0; nt < 4; ++nt){
      acc[nt] = __builtin_amdgcn_mfma_f32_16x16x32_bf16(a0, Bp[(nt*2+0)*64 + lane], z4, 0, 0, 0);
      acc[nt] = __builtin_amdgcn_mfma_f32_16x16x32_bf16(a1, Bp[(nt*2+1)*64 + lane], acc[nt], 0, 0, 0);
    }
    __bf16* base = (p == 1) ? xbH : xrH;
    const int stride = (p == 1) ? 64 : 128;
    const int off0 = (p == 2) ? 64 : 0;
#pragma unroll
    for (int nt = 0; nt < 4; ++nt){
      const int j = nt*16 + m;
      const float bb = (p == 0) ? b1s[j] : 0.f;
#pragma unroll
      for (int r = 0; r < 4; ++r){
        float v = acc[nt][r] + bb;
        unsigned short hu = __builtin_bit_cast(unsigned short, (__bf16)v);
        int pu = __shfl_xor((int)hu, 1);
        if (!(m & 1)){
          const int n = n0 + 16*w + 4*kg + r;
          if (n < NN){
            unsigned word = (unsigned)hu | ((unsigned)(pu & 0xffff) << 16);
            *(unsigned*)(base + (size_t)n*stride + off0 + (j & ~1)) = word;
          }
        }
      }
    }
    if (p == 2){
#pragma unroll
      for (int r = 0; r < 4; ++r){
        float s1 = 0.f, s2 = 0.f;
#pragma unroll
        for (int nt = 0; nt < 4; ++nt){
          s1 = fmaf(acc[nt][r], asrc[nt*16 + m], s1);
          s2 = fmaf(acc[nt][r], adst[nt*16 + m], s2);
        }
#pragma unroll
        for (int o = 8; o; o >>= 1){
          s1 += __shfl_xor(s1, o);
          s2 += __shfl_xor(s2, o);
        }
        if (m == 0){
          const int n = n0 + 16*w + 4*kg + r;
          if (n < NN){ ssrc[n] = s1; sdst[n] = s2; }
        }
      }
    }
  }
}

// ---------------- fused edge MLP (MFMA) + attention logit, 128 edges/block
// xa gather widened to xrH row [xa|xw]; xw half streamed to xwe (sorted order).
__global__ __launch_bounds__(256) void edge_mlp(
    const float* __restrict__ ea0,
    const __bf16* ea_in, __bf16* ea_out,
    const __bf16* __restrict__ xrH, const __bf16* __restrict__ xbH,
    __bf16* __restrict__ xwe,
    const float* __restrict__ ssrc, const float* __restrict__ sdst,
    const int* __restrict__ srow, const int* __restrict__ scol,
    const int* __restrict__ permp,
    const __bf16* __restrict__ w1f, const __bf16* __restrict__ w2f,
    const float* __restrict__ b2v, const float* __restrict__ vv,
    float* __restrict__ lrelu, int store_ea)
{
  __shared__ __align__(16) __bf16 uvh[64*72];     // 9 KB
  __shared__ __align__(16) unsigned ehw[2048];    // 8 KB
  __shared__ float b2s[64], vs[64], sb[128];
  __shared__ int rs[128], cs[128], ps[128];
  const int t = threadIdx.x;
  const int w = t >> 6, l = t & 63, m = l & 15, kg = l >> 4;
  const int eb = blockIdx.x * 128;

  if (t < 128){ rs[t] = srow[eb+t]; cs[t] = scol[eb+t]; }
  else if (t < 192){ b2s[t-128] = b2v[t-128]; vs[t-128] = vv[t-128]; }
  if (permp && t < 128) ps[t] = permp[eb+t];
  __syncthreads();

  const bf16x8* B1 = (const bf16x8*)w1f;
  const bf16x8* B2 = (const bf16x8*)w2f;
  const f32x4 z4 = {0.f, 0.f, 0.f, 0.f};
  const int e_loc = t >> 2, q = t & 3;

  // ======== global load phase ========
  const int r0 = rs[e_loc],      c0 = cs[e_loc];
  const int r1 = rs[64 + e_loc], c1 = cs[64 + e_loc];
  const bf16x8* pr0 = (const bf16x8*)(xrH + (size_t)r0*128 + q*16);
  const bf16x8* pb0 = (const bf16x8*)(xbH + (size_t)c0*64 + q*16);
  const bf16x8* pr1 = (const bf16x8*)(xrH + (size_t)r1*128 + q*16);
  const bf16x8* pb1 = (const bf16x8*)(xbH + (size_t)c1*64 + q*16);
  bf16x8 g_a0l = pr0[0], g_a0h = pr0[1], g_b0l = pb0[0], g_b0h = pb0[1];
  bf16x8 g_a1l = pr1[0], g_a1h = pr1[1], g_b1l = pb1[0], g_b1h = pb1[1];
  bf16x8 w0l = pr0[8], w0h = pr0[9];     // xw half of the same row
  bf16x8 w1l = pr1[8], w1h = pr1[9];
  float sb0 = 0.f, sb1 = 0.f;
  if (q == 0){ sb0 = ssrc[r0] + sdst[c0]; sb1 = ssrc[r1] + sdst[c1]; }

  bf16x8 A00, A01, A10, A11;
  { const int elA = 16*w + m;
    if (ea0){
      const float* s0 = ea0 + (size_t)ps[elA]*64 + kg*8;
      const float* s1 = ea0 + (size_t)ps[64+elA]*64 + kg*8;
      A00 = cvt8(ld4(s0),    ld4(s0+4));  A01 = cvt8(ld4(s0+32), ld4(s0+36));
      A10 = cvt8(ld4(s1),    ld4(s1+4));  A11 = cvt8(ld4(s1+32), ld4(s1+36));
    } else {
      const __bf16* s0 = ea_in + (size_t)(eb+elA)*64 + kg*8;
      const __bf16* s1 = ea_in + (size_t)(eb+64+elA)*64 + kg*8;
      A00 = *(const bf16x8*)s0;  A01 = *(const bf16x8*)(s0+32);
      A10 = *(const bf16x8*)s1;  A11 = *(const bf16x8*)(s1+32);
    }
  }

  // ======== stream xw rows to xwe (sorted order, coalesced) ========
  { __bf16* d0 = xwe + (size_t)(eb + e_loc)*64 + q*16;
    *(bf16x8*)d0 = w0l; *(bf16x8*)(d0+8) = w0h;
    __bf16* d1 = xwe + (size_t)(eb + 64 + e_loc)*64 + q*16;
    *(bf16x8*)d1 = w1l; *(bf16x8*)(d1+8) = w1h; }

  // ======== LDS write: tile-0 uv + both sb ========
  *(bf16x8*)&uvh[e_loc*72 + q*16]     = addpack8(g_a0l, g_b0l);
  *(bf16x8*)&uvh[e_loc*72 + q*16 + 8] = addpack8(g_a0h, g_b0h);
  if (q == 0){ sb[e_loc] = sb0; sb[64 + e_loc] = sb1; }
  asm volatile("" ::: "memory");

  // ======== compute phase ========
  __bf16* esc = (__bf16*)ehw;
  auto tile_compute = [&](bf16x8 a0, bf16x8 a1, int tb){
    f32x4 acc[4];
#pragma unroll
    for (int nt = 0; nt < 4; ++nt){
      acc[nt] = __builtin_amdgcn_mfma_f32_16x16x32_bf16(a0, B1[(nt*2+0)*64 + l], z4, 0, 0, 0);
      acc[nt] = __builtin_amdgcn_mfma_f32_16x16x32_bf16(a1, B1[(nt*2+1)*64 + l], acc[nt], 0, 0, 0);
    }
#pragma unroll
    for (int nt = 0; nt < 4; ++nt){
      const int j = nt*16 + m;
#pragma unroll
      for (int r = 0; r < 4; ++r){
        const int erow = 16*w + 4*kg + r;
        float v = acc[nt][r] + (float)uvh[erow*72 + j];
        v = fmaxf(v, 0.f);
        const int piece = (w*2 + (nt>>1))*64 + (((nt&1)<<1) | (m>>3))*16 + 4*kg + r;
        esc[piece*8 + (m&7)] = (__bf16)v;
      }
    }
    asm volatile("" ::: "memory");
    bf16x8 a20 = *(const bf16x8*)(esc + (size_t)((w*2+0)*64 + kg*16 + m)*8);
    bf16x8 a21 = *(const bf16x8*)(esc + (size_t)((w*2+1)*64 + kg*16 + m)*8);
    f32x4 acc2[4];
#pragma unroll
    for (int nt = 0; nt < 4; ++nt){
      acc2[nt] = __builtin_amdgcn_mfma_f32_16x16x32_bf16(a20, B2[(nt*2+0)*64 + l], z4, 0, 0, 0);
      acc2[nt] = __builtin_amdgcn_mfma_f32_16x16x32_bf16(a21, B2[(nt*2+1)*64 + l], acc2[nt], 0, 0, 0);
    }
    float p0 = 0.f, p1 = 0.f, p2 = 0.f, p3 = 0.f;
#pragma unroll
    for (int nt = 0; nt < 4; ++nt){
      const int j = nt*16 + m;
      const float bj = b2s[j], vj = vs[j];
      float vr[4];
      vr[0] = acc2[nt][0] + bj; vr[1] = acc2[nt][1] + bj;
      vr[2] = acc2[nt][2] + bj; vr[3] = acc2[nt][3] + bj;
      if (store_ea){
        const size_t rowb = (size_t)(eb + tb + 16*w + 4*kg)*64 + (j & ~1);
#pragma unroll
        for (int r = 0; r < 4; ++r){
          unsigned short hu = __builtin_bit_cast(unsigned short, (__bf16)vr[r]);
          int pu = __shfl_xor((int)hu, 1);
          if (!(m & 1)){
            unsigned word = (unsigned)hu | ((unsigned)(pu & 0xffff) << 16);
            *(unsigned*)(ea_out + rowb + (size_t)r*64) = word;
          }
        }
      }
      p0 = fmaf(vr[0], vj, p0); p1 = fmaf(vr[1], vj, p1);
      p2 = fmaf(vr[2], vj, p2); p3 = fmaf(vr[3], vj, p3);
    }
#pragma unroll
    for (int o = 8; o; o >>= 1){
      p0 += __shfl_xor(p0, o); p1 += __shfl_xor(p1, o);
      p2 += __shfl_xor(p2, o); p3 += __shfl_xor(p3, o);
    }
    if (m == 0){
      float pv[4] = {p0, p1, p2, p3};
#pragma unroll
      for (int r = 0; r < 4; ++r){
        const int erow = 16*w + 4*kg + r;
        float logit = sb[tb + erow] + pv[r];
        lrelu[eb + tb + erow] = logit > 0.f ? logit : NEG_SLOPE * logit;
      }
    }
  };

  tile_compute(A00, A01, 0);
  asm volatile("" ::: "memory");
  *(bf16x8*)&uvh[e_loc*72 + q*16]     = addpack8(g_a1l, g_b1l);
  *(bf16x8*)&uvh[e_loc*72 + q*16 + 8] = addpack8(g_a1h, g_b1h);
  asm volatile("" ::: "memory");
  tile_compute(A10, A11, 64);
}

// ---------------- segment softmax + aggregation: xwe stream (no gathers)
__global__ __launch_bounds__(256) void col_agg(
    const float* __restrict__ lrelu, const int* __restrict__ off,
    const __bf16* __restrict__ xwe, float* __restrict__ h)
{
  __shared__ float zS[4][128];
  const int t = threadIdx.x;
  const int lane = t & 63;
  const int wv = t >> 6;
  const int c = blockIdx.x * 4 + wv;
  const int s0 = off[c], s1 = off[c+1];
  const int L = s1 - s0;

  float l0 = (lane < L)    ? lrelu[s0+lane]    : -3.402823466e38f;
  float l1 = (lane+64 < L) ? lrelu[s0+64+lane] : -3.402823466e38f;

  float m = fmaxf(l0, l1);
  for (int i = lane+128; i < L; i += 64) m = fmaxf(m, lrelu[s0+i]);
#pragma unroll
  for (int o = 32; o; o >>= 1) m = fmaxf(m, __shfl_xor(m, o));

  float z0 = (lane < L)    ? expf(l0 - m) : 0.f;
  float z1 = (lane+64 < L) ? expf(l1 - m) : 0.f;
  float s = z0 + z1;
  for (int i = lane+128; i < L; i += 64) s += expf(lrelu[s0+i] - m);
#pragma unroll
  for (int o = 32; o; o >>= 1) s += __shfl_xor(s, o);
  const float inv = 1.f / (s + 1e-16f);

  zS[wv][lane] = z0;  zS[wv][64+lane] = z1;
  asm volatile("" ::: "memory");

  float hv0 = 0.f, hv1 = 0.f, hv2 = 0.f, hv3 = 0.f;
  float hv4 = 0.f, hv5 = 0.f, hv6 = 0.f, hv7 = 0.f;
  const __bf16* xp = xwe + (size_t)s0*64 + lane;
  if (L <= 128){
    int i = 0;
    for (; i + 8 <= L; i += 8){
      hv0 = fmaf(zS[wv][i],   (float)xp[(size_t)(i  )*64], hv0);
      hv1 = fmaf(zS[wv][i+1], (float)xp[(size_t)(i+1)*64], hv1);
      hv2 = fmaf(zS[wv][i+2], (float)xp[(size_t)(i+2)*64], hv2);
      hv3 = fmaf(zS[wv][i+3], (float)xp[(size_t)(i+3)*64], hv3);
      hv4 = fmaf(zS[wv][i+4], (float)xp[(size_t)(i+4)*64], hv4);
      hv5 = fmaf(zS[wv][i+5], (float)xp[(size_t)(i+5)*64], hv5);
      hv6 = fmaf(zS[wv][i+6], (float)xp[(size_t)(i+6)*64], hv6);
      hv7 = fmaf(zS[wv][i+7], (float)xp[(size_t)(i+7)*64], hv7);
    }
    for (; i < L; ++i)
      hv0 = fmaf(zS[wv][i], (float)xp[(size_t)i*64], hv0);
  } else {
    for (int i = 0; i < L; ++i){
      float z = expf(lrelu[s0+i] - m);
      hv0 = fmaf(z, (float)xp[(size_t)i*64], hv0);
    }
  }
  float hv = ((hv0 + hv1) + (hv2 + hv3)) + ((hv4 + hv5) + (hv6 + hv7));
  h[(size_t)c*64 + lane] = hv * inv;
}

// ---------------- BN stats: 64 blocks, atomic-free partials
__global__ __launch_bounds__(256) void bn_stats(
    const float* __restrict__ h, float* __restrict__ bnpart)
{
  const int g = blockIdx.x;
  const int t = threadIdx.x;
  const int d = t & 63, sub = t >> 6;
  const int n0 = g * 782;
  const int n1 = (n0 + 782 < NN) ? n0 + 782 : NN;
  float s = 0.f, s2 = 0.f;
  for (int n = n0 + sub; n < n1; n += 4){
    float v = h[(size_t)n*64 + d];
    s += v; s2 = fmaf(v, v, s2);
  }
  __shared__ float r1[4][64], r2[4][64];
  r1[sub][d] = s; r2[sub][d] = s2;
  __syncthreads();
  if (sub == 0){
    s  = r1[0][d] + r1[1][d] + r1[2][d] + r1[3][d];
    s2 = r2[0][d] + r2[1][d] + r2[2][d] + r2[3][d];
    bnpart[g*128 + d]      = s;
    bnpart[g*128 + 64 + d] = s2;
  }
}

// ---------------- mean pool over graphs, BN+ReLU of layer 2 fused (from partials)
__global__ __launch_bounds__(256) void seg_pool(
    const float* __restrict__ h, const int* __restrict__ goff,
    const float* __restrict__ bnpart,
    const float* __restrict__ gamma2, const float* __restrict__ beta2,
    float* __restrict__ pools, float* __restrict__ pcnt)
{
  __shared__ float sc[64], sh[64];
  const int g = blockIdx.x;
  const int t = threadIdx.x;
  const int d = t & 63, sub = t >> 6;
  if (t < 64){
    float s = 0.f, s2 = 0.f;
#pragma unroll 8
    for (int k = 0; k < 64; ++k){
      s  += bnpart[k*128 + t];
      s2 += bnpart[k*128 + 64 + t];
    }
    float mu  = s * (1.0f / NN);
    float var = s2 * (1.0f / NN) - mu * mu;
    float iv  = rsqrtf(var + 1e-5f) * gamma2[t];
    sc[t] = iv;
    sh[t] = beta2[t] - mu * iv;
  }
  __syncthreads();
  const int s0 = goff[g], s1 = goff[g+1];
  float s = 0.f;
  for (int n = s0 + sub; n < s1; n += 4)
    s += fmaxf(fmaf(h[(size_t)n*64 + d], sc[d], sh[d]), 0.f);
  __shared__ float r[4][64];
  r[sub][d] = s;
  __syncthreads();
  if (sub == 0){
    s = r[0][d] + r[1][d] + r[2][d] + r[3][d];
    pools[g*64 + d] = s;
    if (d == 0) pcnt[g] = (float)(s1 - s0);
  }
}

// ---------------- readout MLP (one block)
__global__ __launch_bounds__(256) void final_mlp(
    const float* __restrict__ pools, const float* __restrict__ pcnt,
    const float* __restrict__ w1, const float* __restrict__ b1,
    const float* __restrict__ w2, const float* __restrict__ b2,
    const float* __restrict__ w3, const float* __restrict__ b3,
    float* __restrict__ out)
{
  __shared__ float g[32*64], h1[32*64], h2[32*32];
  const int t = threadIdx.x;
  for (int i = t; i < 2048; i += 256) g[i] = pools[i] / fmaxf(pcnt[i >> 6], 1.0f);
  __syncthreads();
  for (int i = t; i < 2048; i += 256){
    int gi = i >> 6, d = i & 63;
    float a = b1[d];
    for (int k = 0; k < 64; ++k) a = fmaf(g[gi*64 + k], w1[k*64 + d], a);
    h1[i] = fmaxf(a, 0.f);
  }
  __syncthreads();
  for (int i = t; i < 1024; i += 256){
    int gi = i >> 5, d = i & 31;
    float a = b2[d];
    for (int k = 0; k < 64; ++k) a = fmaf(h1[gi*64 + k], w2[k*32 + d], a);
    h2[i] = fmaxf(a, 0.f);
  }
  __syncthreads();
  if (t < 32){
    float a = b3[0];
    for (int k = 0; k < 32; ++k) a = fmaf(h2[t*32 + k], w3[k], a);
    out[t] = a;
  }
}

extern "C" void kernel_launch(void* const* d_in, const int* in_sizes, int n_in,
                              void* d_out, int out_size, void* d_ws, size_t ws_size,
                              hipStream_t stream)
{
  (void)in_sizes; (void)n_in; (void)out_size; (void)ws_size;
  const float* x0       = (const float*)d_in[0];
  const int*   ei       = (const int*)  d_in[1];
  const float* ea0      = (const float*)d_in[2];
  const int*   batch    = (const int*)  d_in[3];
  const float* em_w1    = (const float*)d_in[4];
  const float* em_b1    = (const float*)d_in[5];
  const float* em_w2    = (const float*)d_in[6];
  const float* em_b2    = (const float*)d_in[7];
  const float* gat_w    = (const float*)d_in[8];
  const float* att_src  = (const float*)d_in[9];
  const float* att_dst  = (const float*)d_in[10];
  const float* edge_w   = (const float*)d_in[11];
  const float* att_edge = (const float*)d_in[12];
  // d_in[13] gat_bias: cancels inside BatchNorm -> unused
  const float* bn_gamma = (const float*)d_in[14];
  const float* bn_beta  = (const float*)d_in[15];
  const float* mlp_w1   = (const float*)d_in[16];
  const float* mlp_b1   = (const float*)d_in[17];
  const float* mlp_w2   = (const float*)d_in[18];
  const float* mlp_b2   = (const float*)d_in[19];
  const float* mlp_w3   = (const float*)d_in[20];
  const float* mlp_b3   = (const float*)d_in[21];
  float* out = (float*)d_out;

  const size_t N64 = (size_t)NN * 64, E64 = (size_t)NE * 64;
  float* ws    = (float*)d_ws;
  float* wsE   = ws;                 // E64 floats: [eaB bf16 E64][xwe bf16 E64]
  float* sxr   = wsE + E64;          // N64 floats -> xrH (N x 128 bf16)
  float* sxb   = sxr + N64;          // N64 floats -> xbH (N x 64 bf16, half used)
  float* hbuf  = sxb + N64;          // N64
  float* bnpart= hbuf + N64;         // 64*128 partials
  float* lrelu = bnpart + 64*128;    // NE
  float* pools = lrelu + NE;         // 2048
  float* pcnt  = pools + 2048;       // 32
  float* ssrc  = pcnt + 32;          // NN
  float* sdst  = ssrc + NN;          // NN
  int*   cnt   = (int*)(sdst + NN);  // NN  -- once memset start
  int*   cur   = cnt + NN;           // NN  -- once memset end
  int*   soff  = cur + NN;           // NN+1
  int*   srow  = soff + NN + 1;      // NE
  int*   scol  = srow + NE;          // NE
  int*   perm  = scol + NE;          // NE
  int*   goff  = perm + NE;          // 33 (pad to 40)
  int*   btot  = goff + 40;          // 196 (pad 256)
  int*   btotex= btot + 256;         // 196 (pad 256)
  __bf16* eaB  = (__bf16*)wsE;
  __bf16* xwe  = (__bf16*)(wsE + E64/2);
  __bf16* xrH  = (__bf16*)sxr;
  __bf16* xbH  = (__bf16*)sxb;
  __bf16* w1f  = (__bf16*)(btotex + 256); // 3*4096 bf16
  __bf16* w2f  = w1f + 3*4096;            // 3*4096 bf16
  __bf16* wnf  = w2f + 3*4096;            // 3*3*4096 bf16
  float* vbuf  = (float*)(wnf + 3*12288); // 3*64 f32

  // ---- one-time per call: setup (hist+bounds+weights), parallel scan, scatter
  hipMemsetAsync(cnt, 0, 2 * NN * sizeof(int), stream);
  setup_kernel<<<NE/256 + 3, 256, 0, stream>>>(
      ei + NE, cnt, batch, goff, em_w1, em_w2, gat_w, edge_w, att_edge,
      w1f, w2f, wnf, vbuf);
  scanA<<<196, 256, 0, stream>>>(cnt, soff, btot);
  scanB<<<1, 256, 0, stream>>>(btot, btotex, soff);
  scanC<<<196, 256, 0, stream>>>(soff, btotex);
  scatter_kernel<<<NE / 256, 256, 0, stream>>>(ei, soff, cur, srow, scol, perm);

  for (int l = 0; l < 3; ++l){
    node_prep<<<(NN + 63) / 64, 256, 0, stream>>>(
        x0, hbuf, bnpart, bn_gamma, bn_beta,
        wnf + (size_t)l*12288, em_b1 + l*64, att_src + l*64, att_dst + l*64,
        xrH, xbH, ssrc, sdst, l);

    edge_mlp<<<NE / 128, 256, 0, stream>>>(
        (l == 0) ? ea0 : nullptr, eaB, eaB, xrH, xbH, xwe, ssrc, sdst,
        srow, scol, (l == 0) ? perm : nullptr,
        w1f + (size_t)l*4096, w2f + (size_t)l*4096,
        em_b2 + l*64, vbuf + l*64, lrelu, (l < 2) ? 1 : 0);

    col_agg<<<NN / 4, 256, 0, stream>>>(lrelu, soff, xwe, hbuf);

    bn_stats<<<64, 256, 0, stream>>>(hbuf, bnpart);
  }

  seg_pool<<<32, 256, 0, stream>>>(hbuf, goff, bnpart,
                                   bn_gamma + 128, bn_beta + 128, pools, pcnt);
  final_mlp<<<1, 256, 0, stream>>>(pools, pcnt, mlp_w1, mlp_b1, mlp_w2, mlp_b2,
                                   mlp_w3, mlp_b3, out);
}

// Round 16
// 748.689 us; speedup vs baseline: 1.1082x; 1.1082x over previous
//
#include <hip/hip_runtime.h>

// GNN forward: 3 x (edge-MLP -> GAT(softmax over col) -> BN+ReLU) -> mean-pool -> MLP.
// Round-16: revert round-15's xwe/xrH routing (regression: +200MB into the
// latency-bound edge_mlp cost more than col_agg's gather). Back to round-14
// structure (best, 788us) with ONE kept change: 3-phase parallel scan
// (replaces the 49-iteration single-block scan).

#define NN 50000
#define NE 800000
#define NEG_SLOPE 0.2f

typedef __attribute__((ext_vector_type(8))) __bf16 bf16x8;
typedef __attribute__((ext_vector_type(4))) float f32x4;

__device__ __forceinline__ float4 ld4(const float* __restrict__ p){ return *(const float4* __restrict__)p; }
__device__ __forceinline__ float4 f4zero(){ return make_float4(0.f,0.f,0.f,0.f); }
__device__ __forceinline__ bf16x8 cvt8(float4 a, float4 b){
  bf16x8 r;
  r[0]=(__bf16)a.x; r[1]=(__bf16)a.y; r[2]=(__bf16)a.z; r[3]=(__bf16)a.w;
  r[4]=(__bf16)b.x; r[5]=(__bf16)b.y; r[6]=(__bf16)b.z; r[7]=(__bf16)b.w;
  return r;
}
__device__ __forceinline__ bf16x8 addpack8(bf16x8 a, bf16x8 b){
  bf16x8 r;
#pragma unroll
  for (int e = 0; e < 8; ++e) r[e] = (__bf16)((float)a[e] + (float)b[e]);
  return r;
}
__device__ __forceinline__ float4 bnrelu4(float4 v, const float* sc, const float* sh, int d){
  return make_float4(
    fmaxf(fmaf(v.x, sc[d+0], sh[d+0]), 0.f),
    fmaxf(fmaf(v.y, sc[d+1], sh[d+1]), 0.f),
    fmaxf(fmaf(v.z, sc[d+2], sh[d+2]), 0.f),
    fmaxf(fmaf(v.w, sc[d+3], sh[d+3]), 0.f));
}

// ---------------- merged setup: hist + graph bounds + weight fragments
__global__ __launch_bounds__(256) void setup_kernel(
    const int* __restrict__ ei_col, int* __restrict__ cnt,
    const int* __restrict__ batch, int* __restrict__ goff,
    const float* __restrict__ em_w1, const float* __restrict__ em_w2,
    const float* __restrict__ gat_w,
    const float* __restrict__ edge_w, const float* __restrict__ att_edge,
    __bf16* __restrict__ w1f, __bf16* __restrict__ w2f, __bf16* __restrict__ wnf,
    float* __restrict__ vbuf)
{
  const int b = blockIdx.x, t = threadIdx.x;
  if (b < NE/256){
    atomicAdd(&cnt[ei_col[b*256 + t]], 1);
    int n = b*256 + t;
    if (n < NN){
      int bn = batch[n];
      int bp = (n == 0) ? -1 : batch[n-1];
      for (int g = bp + 1; g <= bn; ++g) goff[g] = n;
      if (n == NN - 1){ for (int g = bn + 1; g <= 32; ++g) goff[g] = NN; }
    }
  } else {
    const int l = b - NE/256;
    const float* W1c = em_w1 + l*12288 + 8192;   // rows 128..191 of em_w1[l]
    const float* W2  = em_w2 + l*4096;
    for (int p = t; p < 512; p += 256){
      int li = p & 63, ks = (p >> 6) & 1, nt = p >> 7;
      int kbase = ks*32 + (li >> 4)*8;
      int j = nt*16 + (li & 15);
      bf16x8 v1, v2;
#pragma unroll
      for (int e = 0; e < 8; ++e){
        v1[e] = (__bf16)W1c[(size_t)(kbase+e)*64 + j];
        v2[e] = (__bf16)W2[(size_t)(kbase+e)*64 + j];
      }
      *(bf16x8*)(w1f + (size_t)l*4096 + p*8) = v1;
      *(bf16x8*)(w2f + (size_t)l*4096 + p*8) = v2;
    }
    // node GEMM weights: p=0 W1a (rows 0..63), p=1 W1b (rows 64..127), p=2 gat_w
    for (int pp = t; pp < 1536; pp += 256){
      int p = pp >> 9, piece = pp & 511;
      int li = piece & 63, ks = (piece >> 6) & 1, nt = piece >> 7;
      int kbase = ks*32 + (li >> 4)*8;
      int j = nt*16 + (li & 15);
      const float* W = (p == 0) ? (em_w1 + l*12288)
                     : (p == 1) ? (em_w1 + l*12288 + 4096)
                                : (gat_w + l*4096);
      bf16x8 v;
#pragma unroll
      for (int e = 0; e < 8; ++e) v[e] = (__bf16)W[(size_t)(kbase+e)*64 + j];
      *(bf16x8*)(wnf + (size_t)l*12288 + (size_t)p*4096 + piece*8) = v;
    }
    if (t < 64){
      float a = 0.f;
      const float* ew = edge_w + l*4096 + t*64;
      const float* ae = att_edge + l*64;
#pragma unroll 8
      for (int j = 0; j < 64; ++j) a = fmaf(ew[j], ae[j], a);
      vbuf[l*64 + t] = a;
    }
  }
}

// ---------------- 3-phase parallel exclusive scan over NN bins
__global__ __launch_bounds__(256) void scanA(const int* __restrict__ cnt,
                                             int* __restrict__ soff,
                                             int* __restrict__ btot){
  __shared__ int wsum[4];
  const int b = blockIdx.x, t = threadIdx.x;
  const int lane = t & 63, w = t >> 6;
  int idx = b*256 + t;
  int v = (idx < NN) ? cnt[idx] : 0;
  int x = v;
#pragma unroll
  for (int o = 1; o < 64; o <<= 1){
    int u = __shfl_up(x, o);
    if (lane >= o) x += u;
  }
  if (lane == 63) wsum[w] = x;
  __syncthreads();
  int wo = 0;
#pragma unroll
  for (int k = 0; k < 4; ++k) if (k < w) wo += wsum[k];
  int incl = x + wo;
  if (idx < NN) soff[idx] = incl - v;
  if (t == 255) btot[b] = incl;
}
__global__ __launch_bounds__(256) void scanB(const int* __restrict__ btot,
                                             int* __restrict__ btotex,
                                             int* __restrict__ soff){
  __shared__ int wsum[4];
  const int t = threadIdx.x, lane = t & 63, w = t >> 6;
  int v = (t < 196) ? btot[t] : 0;
  int x = v;
#pragma unroll
  for (int o = 1; o < 64; o <<= 1){
    int u = __shfl_up(x, o);
    if (lane >= o) x += u;
  }
  if (lane == 63) wsum[w] = x;
  __syncthreads();
  int wo = 0;
#pragma unroll
  for (int k = 0; k < 4; ++k) if (k < w) wo += wsum[k];
  int incl = x + wo;
  if (t < 196) btotex[t] = incl - v;
  if (t == 195) soff[NN] = incl;
}
__global__ __launch_bounds__(256) void scanC(int* __restrict__ soff,
                                             const int* __restrict__ btotex){
  int idx = blockIdx.x*256 + threadIdx.x;
  if (idx < NN) soff[idx] += btotex[blockIdx.x];
}

// ---------------- sort: scatter into sorted position
__global__ __launch_bounds__(256) void scatter_kernel(
    const int* __restrict__ ei, const int* __restrict__ off, int* __restrict__ cur,
    int* __restrict__ srow, int* __restrict__ scol, int* __restrict__ perm){
  int e = blockIdx.x * 256 + threadIdx.x;
  int r = ei[e], c = ei[NE + e];
  int pos = off[c] + atomicAdd(&cur[c], 1);
  srow[pos] = r; scol[pos] = c; perm[pos] = e;
}

// ---------------- node prep: single pass, MFMA (round-14 structure)
__global__ __launch_bounds__(256) void node_prep(
    const float* __restrict__ x0_in, const float* __restrict__ h_in,
    const float* __restrict__ bnpart,
    const float* __restrict__ gamma, const float* __restrict__ beta,
    const __bf16* __restrict__ wnf_l,
    const float* __restrict__ b1v,
    const float* __restrict__ asrc_g, const float* __restrict__ adst_g,
    __bf16* __restrict__ xaH, __bf16* __restrict__ xbH, __bf16* __restrict__ xwH,
    float* __restrict__ ssrc, float* __restrict__ sdst, int l)
{
  __shared__ __align__(16) __bf16 xf[64*72];
  __shared__ float sc[64], sh[64];
  __shared__ float b1s[64], asrc[64], adst[64];
  const int t = threadIdx.x;
  const int n0 = blockIdx.x * 64;
  const int w = t >> 6, lane = t & 63, m = lane & 15, kg = lane >> 4;

  if (l > 0){
    if (t < 64){
      float s = 0.f, s2 = 0.f;
#pragma unroll 8
      for (int k = 0; k < 64; ++k){
        s  += bnpart[k*128 + t];
        s2 += bnpart[k*128 + 64 + t];
      }
      float mu  = s * (1.0f / NN);
      float var = s2 * (1.0f / NN) - mu * mu;
      float iv  = rsqrtf(var + 1e-5f) * gamma[(l-1)*64 + t];
      sc[t] = iv;
      sh[t] = beta[(l-1)*64 + t] - mu * iv;
    }
    __syncthreads();
  }
  if (t < 64) b1s[t] = b1v[t];
  else if (t < 128) asrc[t-64] = asrc_g[t-64];
  else if (t < 192) adst[t-128] = adst_g[t-128];

  { const int e_loc = t >> 2, q = t & 3;
    const int n = n0 + e_loc;
    float4 v0, v1, v2, v3;
    if (n < NN){
      const float* src = ((l == 0) ? x0_in : h_in) + (size_t)n*64 + q*16;
      v0 = ld4(src); v1 = ld4(src+4); v2 = ld4(src+8); v3 = ld4(src+12);
      if (l > 0){
        v0 = bnrelu4(v0, sc, sh, q*16);
        v1 = bnrelu4(v1, sc, sh, q*16+4);
        v2 = bnrelu4(v2, sc, sh, q*16+8);
        v3 = bnrelu4(v3, sc, sh, q*16+12);
      }
    } else { v0 = v1 = v2 = v3 = f4zero(); }
    *(bf16x8*)&xf[e_loc*72 + q*16]     = cvt8(v0, v1);
    *(bf16x8*)&xf[e_loc*72 + q*16 + 8] = cvt8(v2, v3);
  }
  __syncthreads();

  const bf16x8 a0 = *(const bf16x8*)&xf[(16*w + m)*72 + kg*8];
  const bf16x8 a1 = *(const bf16x8*)&xf[(16*w + m)*72 + kg*8 + 32];
  const f32x4 z4 = {0.f, 0.f, 0.f, 0.f};

#pragma unroll
  for (int p = 0; p < 3; ++p){
    const bf16x8* Bp = (const bf16x8*)(wnf_l + (size_t)p*4096);
    f32x4 acc[4];
#pragma unroll
    for (int nt = 0; nt < 4; ++nt){
      acc[nt] = __builtin_amdgcn_mfma_f32_16x16x32_bf16(a0, Bp[(nt*2+0)*64 + lane], z4, 0, 0, 0);
      acc[nt] = __builtin_amdgcn_mfma_f32_16x16x32_bf16(a1, Bp[(nt*2+1)*64 + lane], acc[nt], 0, 0, 0);
    }
    __bf16* op = (p == 0) ? xaH : (p == 1) ? xbH : xwH;
#pragma unroll
    for (int nt = 0; nt < 4; ++nt){
      const int j = nt*16 + m;
      const float bb = (p == 0) ? b1s[j] : 0.f;
#pragma unroll
      for (int r = 0; r < 4; ++r){
        float v = acc[nt][r] + bb;
        unsigned short hu = __builtin_bit_cast(unsigned short, (__bf16)v);
        int pu = __shfl_xor((int)hu, 1);
        if (!(m & 1)){
          const int n = n0 + 16*w + 4*kg + r;
          if (n < NN){
            unsigned word = (unsigned)hu | ((unsigned)(pu & 0xffff) << 16);
            *(unsigned*)(op + (size_t)n*64 + (j & ~1)) = word;
          }
        }
      }
    }
    if (p == 2){
#pragma unroll
      for (int r = 0; r < 4; ++r){
        float s1 = 0.f, s2 = 0.f;
#pragma unroll
        for (int nt = 0; nt < 4; ++nt){
          s1 = fmaf(acc[nt][r], asrc[nt*16 + m], s1);
          s2 = fmaf(acc[nt][r], adst[nt*16 + m], s2);
        }
#pragma unroll
        for (int o = 8; o; o >>= 1){
          s1 += __shfl_xor(s1, o);
          s2 += __shfl_xor(s2, o);
        }
        if (m == 0){
          const int n = n0 + 16*w + 4*kg + r;
          if (n < NN){ ssrc[n] = s1; sdst[n] = s2; }
        }
      }
    }
  }
}

// ---------------- fused edge MLP (MFMA) + attention logit, 128 edges/block
// Round-12/14 structure (proven 131us floor).
__global__ __launch_bounds__(256) void edge_mlp(
    const float* __restrict__ ea0,
    const __bf16* ea_in, __bf16* ea_out,
    const __bf16* __restrict__ xaH, const __bf16* __restrict__ xbH,
    const float* __restrict__ ssrc, const float* __restrict__ sdst,
    const int* __restrict__ srow, const int* __restrict__ scol,
    const int* __restrict__ permp,
    const __bf16* __restrict__ w1f, const __bf16* __restrict__ w2f,
    const float* __restrict__ b2v, const float* __restrict__ vv,
    float* __restrict__ lrelu, int store_ea)
{
  __shared__ __align__(16) __bf16 uvh[64*72];     // 9 KB
  __shared__ __align__(16) unsigned ehw[2048];    // 8 KB
  __shared__ float b2s[64], vs[64], sb[128];
  __shared__ int rs[128], cs[128], ps[128];
  const int t = threadIdx.x;
  const int w = t >> 6, l = t & 63, m = l & 15, kg = l >> 4;
  const int eb = blockIdx.x * 128;

  if (t < 128){ rs[t] = srow[eb+t]; cs[t] = scol[eb+t]; }
  else if (t < 192){ b2s[t-128] = b2v[t-128]; vs[t-128] = vv[t-128]; }
  if (permp && t < 128) ps[t] = permp[eb+t];
  __syncthreads();

  const bf16x8* B1 = (const bf16x8*)w1f;
  const bf16x8* B2 = (const bf16x8*)w2f;
  const f32x4 z4 = {0.f, 0.f, 0.f, 0.f};
  const int e_loc = t >> 2, q = t & 3;

  // ======== global load phase: everything issued before any fence ========
  const int r0 = rs[e_loc],      c0 = cs[e_loc];
  const int r1 = rs[64 + e_loc], c1 = cs[64 + e_loc];
  const bf16x8* pa0 = (const bf16x8*)(xaH + (size_t)r0*64 + q*16);
  const bf16x8* pb0 = (const bf16x8*)(xbH + (size_t)c0*64 + q*16);
  const bf16x8* pa1 = (const bf16x8*)(xaH + (size_t)r1*64 + q*16);
  const bf16x8* pb1 = (const bf16x8*)(xbH + (size_t)c1*64 + q*16);
  bf16x8 g_a0l = pa0[0], g_a0h = pa0[1], g_b0l = pb0[0], g_b0h = pb0[1];
  bf16x8 g_a1l = pa1[0], g_a1h = pa1[1], g_b1l = pb1[0], g_b1h = pb1[1];
  float sb0 = 0.f, sb1 = 0.f;
  if (q == 0){ sb0 = ssrc[r0] + sdst[c0]; sb1 = ssrc[r1] + sdst[c1]; }

  bf16x8 A00, A01, A10, A11;
  { const int elA = 16*w + m;
    if (ea0){
      const float* s0 = ea0 + (size_t)ps[elA]*64 + kg*8;
      const float* s1 = ea0 + (size_t)ps[64+elA]*64 + kg*8;
      A00 = cvt8(ld4(s0),    ld4(s0+4));  A01 = cvt8(ld4(s0+32), ld4(s0+36));
      A10 = cvt8(ld4(s1),    ld4(s1+4));  A11 = cvt8(ld4(s1+32), ld4(s1+36));
    } else {
      const __bf16* s0 = ea_in + (size_t)(eb+elA)*64 + kg*8;
      const __bf16* s1 = ea_in + (size_t)(eb+64+elA)*64 + kg*8;
      A00 = *(const bf16x8*)s0;  A01 = *(const bf16x8*)(s0+32);
      A10 = *(const bf16x8*)s1;  A11 = *(const bf16x8*)(s1+32);
    }
  }

  // ======== LDS write: tile-0 uv + both sb ========
  *(bf16x8*)&uvh[e_loc*72 + q*16]     = addpack8(g_a0l, g_b0l);
  *(bf16x8*)&uvh[e_loc*72 + q*16 + 8] = addpack8(g_a0h, g_b0h);
  if (q == 0){ sb[e_loc] = sb0; sb[64 + e_loc] = sb1; }
  asm volatile("" ::: "memory");

  // ======== compute phase: VGPR/LDS only ========
  __bf16* esc = (__bf16*)ehw;
  auto tile_compute = [&](bf16x8 a0, bf16x8 a1, int tb){
    f32x4 acc[4];
#pragma unroll
    for (int nt = 0; nt < 4; ++nt){
      acc[nt] = __builtin_amdgcn_mfma_f32_16x16x32_bf16(a0, B1[(nt*2+0)*64 + l], z4, 0, 0, 0);
      acc[nt] = __builtin_amdgcn_mfma_f32_16x16x32_bf16(a1, B1[(nt*2+1)*64 + l], acc[nt], 0, 0, 0);
    }
#pragma unroll
    for (int nt = 0; nt < 4; ++nt){
      const int j = nt*16 + m;
#pragma unroll
      for (int r = 0; r < 4; ++r){
        const int erow = 16*w + 4*kg + r;
        float v = acc[nt][r] + (float)uvh[erow*72 + j];
        v = fmaxf(v, 0.f);
        const int piece = (w*2 + (nt>>1))*64 + (((nt&1)<<1) | (m>>3))*16 + 4*kg + r;
        esc[piece*8 + (m&7)] = (__bf16)v;
      }
    }
    asm volatile("" ::: "memory");
    bf16x8 a20 = *(const bf16x8*)(esc + (size_t)((w*2+0)*64 + kg*16 + m)*8);
    bf16x8 a21 = *(const bf16x8*)(esc + (size_t)((w*2+1)*64 + kg*16 + m)*8);
    f32x4 acc2[4];
#pragma unroll
    for (int nt = 0; nt < 4; ++nt){
      acc2[nt] = __builtin_amdgcn_mfma_f32_16x16x32_bf16(a20, B2[(nt*2+0)*64 + l], z4, 0, 0, 0);
      acc2[nt] = __builtin_amdgcn_mfma_f32_16x16x32_bf16(a21, B2[(nt*2+1)*64 + l], acc2[nt], 0, 0, 0);
    }
    float p0 = 0.f, p1 = 0.f, p2 = 0.f, p3 = 0.f;
#pragma unroll
    for (int nt = 0; nt < 4; ++nt){
      const int j = nt*16 + m;
      const float bj = b2s[j], vj = vs[j];
      float vr[4];
      vr[0] = acc2[nt][0] + bj; vr[1] = acc2[nt][1] + bj;
      vr[2] = acc2[nt][2] + bj; vr[3] = acc2[nt][3] + bj;
      if (store_ea){
        const size_t rowb = (size_t)(eb + tb + 16*w + 4*kg)*64 + (j & ~1);
#pragma unroll
        for (int r = 0; r < 4; ++r){
          unsigned short hu = __builtin_bit_cast(unsigned short, (__bf16)vr[r]);
          int pu = __shfl_xor((int)hu, 1);
          if (!(m & 1)){
            unsigned word = (unsigned)hu | ((unsigned)(pu & 0xffff) << 16);
            *(unsigned*)(ea_out + rowb + (size_t)r*64) = word;
          }
        }
      }
      p0 = fmaf(vr[0], vj, p0); p1 = fmaf(vr[1], vj, p1);
      p2 = fmaf(vr[2], vj, p2); p3 = fmaf(vr[3], vj, p3);
    }
#pragma unroll
    for (int o = 8; o; o >>= 1){
      p0 += __shfl_xor(p0, o); p1 += __shfl_xor(p1, o);
      p2 += __shfl_xor(p2, o); p3 += __shfl_xor(p3, o);
    }
    if (m == 0){
      float pv[4] = {p0, p1, p2, p3};
#pragma unroll
      for (int r = 0; r < 4; ++r){
        const int erow = 16*w + 4*kg + r;
        float logit = sb[tb + erow] + pv[r];
        lrelu[eb + tb + erow] = logit > 0.f ? logit : NEG_SLOPE * logit;
      }
    }
  };

  tile_compute(A00, A01, 0);
  asm volatile("" ::: "memory");
  *(bf16x8*)&uvh[e_loc*72 + q*16]     = addpack8(g_a1l, g_b1l);
  *(bf16x8*)&uvh[e_loc*72 + q*16 + 8] = addpack8(g_a1h, g_b1h);
  asm volatile("" ::: "memory");
  tile_compute(A10, A11, 64);
}

// ---------------- segment softmax + aggregation: one wave per col, 8-way unrolled
__global__ __launch_bounds__(256) void col_agg(
    const float* __restrict__ lrelu, const int* __restrict__ srow,
    const int* __restrict__ off, const __bf16* __restrict__ xwH,
    float* __restrict__ h)
{
  __shared__ float zS[4][128];
  __shared__ int   rS[4][128];
  const int t = threadIdx.x;
  const int lane = t & 63;
  const int wv = t >> 6;
  const int c = blockIdx.x * 4 + wv;
  const int s0 = off[c], s1 = off[c+1];
  const int L = s1 - s0;

  float l0 = (lane < L)    ? lrelu[s0+lane]    : -3.402823466e38f;
  float l1 = (lane+64 < L) ? lrelu[s0+64+lane] : -3.402823466e38f;
  int   r0 = (lane < L)    ? srow[s0+lane]     : 0;
  int   r1 = (lane+64 < L) ? srow[s0+64+lane]  : 0;

  float m = fmaxf(l0, l1);
  for (int i = lane+128; i < L; i += 64) m = fmaxf(m, lrelu[s0+i]);
#pragma unroll
  for (int o = 32; o; o >>= 1) m = fmaxf(m, __shfl_xor(m, o));

  float z0 = (lane < L)    ? expf(l0 - m) : 0.f;
  float z1 = (lane+64 < L) ? expf(l1 - m) : 0.f;
  float s = z0 + z1;
  for (int i = lane+128; i < L; i += 64) s += expf(lrelu[s0+i] - m);
#pragma unroll
  for (int o = 32; o; o >>= 1) s += __shfl_xor(s, o);
  const float inv = 1.f / (s + 1e-16f);

  zS[wv][lane] = z0;  zS[wv][64+lane] = z1;
  rS[wv][lane] = r0;  rS[wv][64+lane] = r1;
  asm volatile("" ::: "memory");

  float hv0 = 0.f, hv1 = 0.f, hv2 = 0.f, hv3 = 0.f;
  float hv4 = 0.f, hv5 = 0.f, hv6 = 0.f, hv7 = 0.f;
  if (L <= 128){
    int i = 0;
    for (; i + 8 <= L; i += 8){
      float za = zS[wv][i],   zb = zS[wv][i+1], zc = zS[wv][i+2], zd = zS[wv][i+3];
      float ze = zS[wv][i+4], zf = zS[wv][i+5], zg = zS[wv][i+6], zh = zS[wv][i+7];
      int   ra = rS[wv][i],   rb = rS[wv][i+1], rc = rS[wv][i+2], rd = rS[wv][i+3];
      int   re = rS[wv][i+4], rf = rS[wv][i+5], rg = rS[wv][i+6], rh = rS[wv][i+7];
      hv0 = fmaf(za, (float)xwH[(size_t)ra*64 + lane], hv0);
      hv1 = fmaf(zb, (float)xwH[(size_t)rb*64 + lane], hv1);
      hv2 = fmaf(zc, (float)xwH[(size_t)rc*64 + lane], hv2);
      hv3 = fmaf(zd, (float)xwH[(size_t)rd*64 + lane], hv3);
      hv4 = fmaf(ze, (float)xwH[(size_t)re*64 + lane], hv4);
      hv5 = fmaf(zf, (float)xwH[(size_t)rf*64 + lane], hv5);
      hv6 = fmaf(zg, (float)xwH[(size_t)rg*64 + lane], hv6);
      hv7 = fmaf(zh, (float)xwH[(size_t)rh*64 + lane], hv7);
    }
    for (; i < L; ++i)
      hv0 = fmaf(zS[wv][i], (float)xwH[(size_t)rS[wv][i]*64 + lane], hv0);
  } else {
    for (int i = 0; i < L; ++i){
      float z = expf(lrelu[s0+i] - m);
      int r = srow[s0+i];
      hv0 = fmaf(z, (float)xwH[(size_t)r*64 + lane], hv0);
    }
  }
  float hv = ((hv0 + hv1) + (hv2 + hv3)) + ((hv4 + hv5) + (hv6 + hv7));
  h[(size_t)c*64 + lane] = hv * inv;
}

// ---------------- BN stats: 64 blocks, atomic-free partials
__global__ __launch_bounds__(256) void bn_stats(
    const float* __restrict__ h, float* __restrict__ bnpart)
{
  const int g = blockIdx.x;
  const int t = threadIdx.x;
  const int d = t & 63, sub = t >> 6;
  const int n0 = g * 782;
  const int n1 = (n0 + 782 < NN) ? n0 + 782 : NN;
  float s = 0.f, s2 = 0.f;
  for (int n = n0 + sub; n < n1; n += 4){
    float v = h[(size_t)n*64 + d];
    s += v; s2 = fmaf(v, v, s2);
  }
  __shared__ float r1[4][64], r2[4][64];
  r1[sub][d] = s; r2[sub][d] = s2;
  __syncthreads();
  if (sub == 0){
    s  = r1[0][d] + r1[1][d] + r1[2][d] + r1[3][d];
    s2 = r2[0][d] + r2[1][d] + r2[2][d] + r2[3][d];
    bnpart[g*128 + d]      = s;
    bnpart[g*128 + 64 + d] = s2;
  }
}

// ---------------- mean pool over graphs, BN+ReLU of layer 2 fused (from partials)
__global__ __launch_bounds__(256) void seg_pool(
    const float* __restrict__ h, const int* __restrict__ goff,
    const float* __restrict__ bnpart,
    const float* __restrict__ gamma2, const float* __restrict__ beta2,
    float* __restrict__ pools, float* __restrict__ pcnt)
{
  __shared__ float sc[64], sh[64];
  const int g = blockIdx.x;
  const int t = threadIdx.x;
  const int d = t & 63, sub = t >> 6;
  if (t < 64){
    float s = 0.f, s2 = 0.f;
#pragma unroll 8
    for (int k = 0; k < 64; ++k){
      s  += bnpart[k*128 + t];
      s2 += bnpart[k*128 + 64 + t];
    }
    float mu  = s * (1.0f / NN);
    float var = s2 * (1.0f / NN) - mu * mu;
    float iv  = rsqrtf(var + 1e-5f) * gamma2[t];
    sc[t] = iv;
    sh[t] = beta2[t] - mu * iv;
  }
  __syncthreads();
  const int s0 = goff[g], s1 = goff[g+1];
  float s = 0.f;
  for (int n = s0 + sub; n < s1; n += 4)
    s += fmaxf(fmaf(h[(size_t)n*64 + d], sc[d], sh[d]), 0.f);
  __shared__ float r[4][64];
  r[sub][d] = s;
  __syncthreads();
  if (sub == 0){
    s = r[0][d] + r[1][d] + r[2][d] + r[3][d];
    pools[g*64 + d] = s;
    if (d == 0) pcnt[g] = (float)(s1 - s0);
  }
}

// ---------------- readout MLP (one block)
__global__ __launch_bounds__(256) void final_mlp(
    const float* __restrict__ pools, const float* __restrict__ pcnt,
    const float* __restrict__ w1, const float* __restrict__ b1,
    const float* __restrict__ w2, const float* __restrict__ b2,
    const float* __restrict__ w3, const float* __restrict__ b3,
    float* __restrict__ out)
{
  __shared__ float g[32*64], h1[32*64], h2[32*32];
  const int t = threadIdx.x;
  for (int i = t; i < 2048; i += 256) g[i] = pools[i] / fmaxf(pcnt[i >> 6], 1.0f);
  __syncthreads();
  for (int i = t; i < 2048; i += 256){
    int gi = i >> 6, d = i & 63;
    float a = b1[d];
    for (int k = 0; k < 64; ++k) a = fmaf(g[gi*64 + k], w1[k*64 + d], a);
    h1[i] = fmaxf(a, 0.f);
  }
  __syncthreads();
  for (int i = t; i < 1024; i += 256){
    int gi = i >> 5, d = i & 31;
    float a = b2[d];
    for (int k = 0; k < 64; ++k) a = fmaf(h1[gi*64 + k], w2[k*32 + d], a);
    h2[i] = fmaxf(a, 0.f);
  }
  __syncthreads();
  if (t < 32){
    float a = b3[0];
    for (int k = 0; k < 32; ++k) a = fmaf(h2[t*32 + k], w3[k], a);
    out[t] = a;
  }
}

extern "C" void kernel_launch(void* const* d_in, const int* in_sizes, int n_in,
                              void* d_out, int out_size, void* d_ws, size_t ws_size,
                              hipStream_t stream)
{
  (void)in_sizes; (void)n_in; (void)out_size; (void)ws_size;
  const float* x0       = (const float*)d_in[0];
  const int*   ei       = (const int*)  d_in[1];
  const float* ea0      = (const float*)d_in[2];
  const int*   batch    = (const int*)  d_in[3];
  const float* em_w1    = (const float*)d_in[4];
  const float* em_b1    = (const float*)d_in[5];
  const float* em_w2    = (const float*)d_in[6];
  const float* em_b2    = (const float*)d_in[7];
  const float* gat_w    = (const float*)d_in[8];
  const float* att_src  = (const float*)d_in[9];
  const float* att_dst  = (const float*)d_in[10];
  const float* edge_w   = (const float*)d_in[11];
  const float* att_edge = (const float*)d_in[12];
  // d_in[13] gat_bias: cancels inside BatchNorm -> unused
  const float* bn_gamma = (const float*)d_in[14];
  const float* bn_beta  = (const float*)d_in[15];
  const float* mlp_w1   = (const float*)d_in[16];
  const float* mlp_b1   = (const float*)d_in[17];
  const float* mlp_w2   = (const float*)d_in[18];
  const float* mlp_b2   = (const float*)d_in[19];
  const float* mlp_w3   = (const float*)d_in[20];
  const float* mlp_b3   = (const float*)d_in[21];
  float* out = (float*)d_out;

  const size_t N64 = (size_t)NN * 64, E64 = (size_t)NE * 64;
  float* ws    = (float*)d_ws;
  float* wsE   = ws;                 // E64 f32 slots; bf16 edge_attr (sorted)
  float* sxa   = wsE + E64;          // N64 f32 slot -> bf16 xaH
  float* sxb   = sxa + N64;          // N64 f32 slot -> bf16 xbH
  float* sxw   = sxb + N64;          // N64 f32 slot -> bf16 xwH
  float* hbuf  = sxw + N64;          // N64
  float* bnpart= hbuf + N64;         // 64*128 partials
  float* lrelu = bnpart + 64*128;    // NE
  float* pools = lrelu + NE;         // 2048
  float* pcnt  = pools + 2048;       // 32
  float* ssrc  = pcnt + 32;          // NN
  float* sdst  = ssrc + NN;          // NN
  int*   cnt   = (int*)(sdst + NN);  // NN  -- once memset start
  int*   cur   = cnt + NN;           // NN  -- once memset end
  int*   soff  = cur + NN;           // NN+1
  int*   srow  = soff + NN + 1;      // NE
  int*   scol  = srow + NE;          // NE
  int*   perm  = scol + NE;          // NE
  int*   goff  = perm + NE;          // 33 (pad to 40)
  int*   btot  = goff + 40;          // 196 (pad 256)
  int*   btotex= btot + 256;         // 196 (pad 256)
  __bf16* eaB  = (__bf16*)wsE;
  __bf16* xaH  = (__bf16*)sxa;
  __bf16* xbH  = (__bf16*)sxb;
  __bf16* xwH  = (__bf16*)sxw;
  __bf16* w1f  = (__bf16*)(btotex + 256); // 3*4096 bf16
  __bf16* w2f  = w1f + 3*4096;            // 3*4096 bf16
  __bf16* wnf  = w2f + 3*4096;            // 3*3*4096 bf16
  float* vbuf  = (float*)(wnf + 3*12288); // 3*64 f32

  // ---- one-time per call: setup, 3-phase scan, scatter
  hipMemsetAsync(cnt, 0, 2 * NN * sizeof(int), stream);
  setup_kernel<<<NE/256 + 3, 256, 0, stream>>>(
      ei + NE, cnt, batch, goff, em_w1, em_w2, gat_w, edge_w, att_edge,
      w1f, w2f, wnf, vbuf);
  scanA<<<196, 256, 0, stream>>>(cnt, soff, btot);
  scanB<<<1, 256, 0, stream>>>(btot, btotex, soff);
  scanC<<<196, 256, 0, stream>>>(soff, btotex);
  scatter_kernel<<<NE / 256, 256, 0, stream>>>(ei, soff, cur, srow, scol, perm);

  for (int l = 0; l < 3; ++l){
    node_prep<<<(NN + 63) / 64, 256, 0, stream>>>(
        x0, hbuf, bnpart, bn_gamma, bn_beta,
        wnf + (size_t)l*12288, em_b1 + l*64, att_src + l*64, att_dst + l*64,
        xaH, xbH, xwH, ssrc, sdst, l);

    edge_mlp<<<NE / 128, 256, 0, stream>>>(
        (l == 0) ? ea0 : nullptr, eaB, eaB, xaH, xbH, ssrc, sdst,
        srow, scol, (l == 0) ? perm : nullptr,
        w1f + (size_t)l*4096, w2f + (size_t)l*4096,
        em_b2 + l*64, vbuf + l*64, lrelu, (l < 2) ? 1 : 0);

    col_agg<<<NN / 4, 256, 0, stream>>>(lrelu, srow, soff, xwH, hbuf);

    bn_stats<<<64, 256, 0, stream>>>(hbuf, bnpart);
  }

  seg_pool<<<32, 256, 0, stream>>>(hbuf, goff, bnpart,
                                   bn_gamma + 128, bn_beta + 128, pools, pcnt);
  final_mlp<<<1, 256, 0, stream>>>(pools, pcnt, mlp_w1, mlp_b1, mlp_w2, mlp_b2,
                                   mlp_w3, mlp_b3, out);
}